// Round 5
// baseline (16750.931 us; speedup 1.0000x reference)
//
#include <hip/hip_runtime.h>
#include <hip/hip_fp16.h>
#include <math.h>

// Problem dims (fixed)
#define T_SEQ 4096
#define DIN   64
#define DM    1024
#define G4    4096              // 4*DM gate rows
#define LSTRIDE_W ((size_t)G4 * DM)   // per-layer Wih/Whh stride
#define LSTRIDE_B ((size_t)G4)        // per-layer bias stride

#define SENT 0x7FC0DEADu        // qNaN payload: unreachable as an h0 value

// sleep quanta: s_sleep(4) ~ 256 cy. Adaptive counts are in these units.
#define SLP_INIT 9              // ~2300 cy starting point (R14's S_RING)
#define SLP_MIN  4              // ~1024 cy
#define SLP_MAX  24             // ~6144 cy
#define SLP_UP   3              // +768 cy on any first-poll miss in the WG
#define SLP_DN   1              // -256 cy on a clean round
#define S_RETRY  2              // ~128 cy retry pacing (load RT dominates)
#define S_HIST   8              // ~512 cy: L1 catch-up when L0 is behind

typedef unsigned long long u64;
typedef unsigned int u32;

// sleep + compiler memory fence (prevent hoisting atomic loads above it)
#define PAUSE(n) do { __builtin_amdgcn_s_sleep(n); asm volatile("" ::: "memory"); } while (0)

__device__ __forceinline__ float sigmoidf_(float x) {
    return 1.0f / (1.0f + __expf(-x));
}
__device__ __forceinline__ float tanhf_(float x) {
    float ax = fabsf(x);
    float e  = __expf(-2.0f * ax);
    float t  = (1.0f - e) / (1.0f + e);
    return copysignf(t, x);
}
__device__ __forceinline__ float lrelu_(float x) {
    return x > 0.0f ? x : 0.01f * x;
}

// pack two fp32 -> one u32 of two f16 (v_cvt_pkrtz_f16_f32)
__device__ __forceinline__ u32 pk2_(float x, float y) {
    typedef __fp16 hv2 __attribute__((ext_vector_type(2)));
    union { hv2 h; u32 u; } c;
    c.h = __builtin_amdgcn_cvt_pkrtz(x, y);
    return c.u;
}
// fused f16-pair dot-accumulate: acc += a.x*b.x + a.y*b.y
#if __has_builtin(__builtin_amdgcn_fdot2)
__device__ __forceinline__ float d2a_(u32 a, u32 b, float acc) {
    typedef __fp16 hv2 __attribute__((ext_vector_type(2)));
    union { u32 u; hv2 h; } ua, ub;
    ua.u = a; ub.u = b;
    return __builtin_amdgcn_fdot2(ua.h, ub.h, acc, false);
}
#else
__device__ __forceinline__ float d2a_(u32 a, u32 b, float acc) {
    union { u32 u; __half2 h; } ua, ub;
    ua.u = a; ub.u = b;
    float2 fa = __half22float2(ua.h);
    float2 fb = __half22float2(ub.h);
    return acc + fa.x * fb.x + fa.y * fb.y;
}
#endif
__device__ __forceinline__ float dot8a_(uint4 q, uint4 h, float acc) {
    acc = d2a_(q.x, h.x, acc);
    acc = d2a_(q.y, h.y, acc);
    acc = d2a_(q.z, h.z, acc);
    acc = d2a_(q.w, h.w, acc);
    return acc;
}

// ---------------------------------------------------------------------------
// K1: x[t,d] = leaky_relu(sum_k inp[t,k]*W1[d,k] + b1[d]);  grid=4096, block=256
// ---------------------------------------------------------------------------
__global__ __launch_bounds__(256) void k_input(const float* __restrict__ inp,
                                               const float* __restrict__ W1,
                                               const float* __restrict__ b1,
                                               float* __restrict__ x) {
    __shared__ float s_in[DIN];
    const int t   = blockIdx.x;
    const int tid = threadIdx.x;
    if (tid < DIN) s_in[tid] = inp[(size_t)t * DIN + tid];
    __syncthreads();
#pragma unroll
    for (int q = 0; q < 4; q++) {
        const int d = tid + q * 256;
        const float4* wr = (const float4*)(W1 + (size_t)d * DIN);
        float acc = 0.0f;
#pragma unroll
        for (int e = 0; e < 16; e++) {
            float4 w = wr[e];
            acc += w.x * s_in[e * 4 + 0] + w.y * s_in[e * 4 + 1] +
                   w.z * s_in[e * 4 + 2] + w.w * s_in[e * 4 + 3];
        }
        acc += b1[d];
        x[(size_t)t * DM + d] = lrelu_(acc);
    }
}

// ---------------------------------------------------------------------------
// K2: xg[m,n] = sum_k x[m,k]*Wih0[n,k] + (bih0[n]+bhh0[n])
// 128x128 tile, BK=16, 256 threads, 8x8 per thread.
// ---------------------------------------------------------------------------
__global__ __launch_bounds__(256) void k_gemm(const float* __restrict__ A,
                                              const float* __restrict__ B,
                                              const float* __restrict__ bih,
                                              const float* __restrict__ bhh,
                                              float* __restrict__ C) {
    const int K = DM;
    __shared__ float As[16][132];
    __shared__ float Bs[16][132];
    const int tid = threadIdx.x;
    const int m0 = blockIdx.y * 128, n0 = blockIdx.x * 128;
    const int tx = tid & 15, ty = tid >> 4;
    const int lr = tid >> 1;
    const int lc = (tid & 1) * 8;

    float acc[8][8] = {};
    const float4* ag = (const float4*)(A + (size_t)(m0 + lr) * K + lc);
    const float4* bg = (const float4*)(B + (size_t)(n0 + lr) * K + lc);

    for (int k0 = 0; k0 < K; k0 += 16) {
        float4 a0 = ag[0], a1 = ag[1];
        float4 b0 = bg[0], b1v = bg[1];
        ag += 4; bg += 4;
        __syncthreads();
        As[lc + 0][lr] = a0.x; As[lc + 1][lr] = a0.y; As[lc + 2][lr] = a0.z; As[lc + 3][lr] = a0.w;
        As[lc + 4][lr] = a1.x; As[lc + 5][lr] = a1.y; As[lc + 6][lr] = a1.z; As[lc + 7][lr] = a1.w;
        Bs[lc + 0][lr] = b0.x; Bs[lc + 1][lr] = b0.y; Bs[lc + 2][lr] = b0.z; Bs[lc + 3][lr] = b0.w;
        Bs[lc + 4][lr] = b1v.x; Bs[lc + 5][lr] = b1v.y; Bs[lc + 6][lr] = b1v.z; Bs[lc + 7][lr] = b1v.w;
        __syncthreads();
#pragma unroll
        for (int k = 0; k < 16; k++) {
            float a[8], b[8];
            *(float4*)&a[0] = *(const float4*)&As[k][ty * 8 + 0];
            *(float4*)&a[4] = *(const float4*)&As[k][ty * 8 + 4];
            *(float4*)&b[0] = *(const float4*)&Bs[k][tx * 8 + 0];
            *(float4*)&b[4] = *(const float4*)&Bs[k][tx * 8 + 4];
#pragma unroll
            for (int i = 0; i < 8; i++)
#pragma unroll
                for (int j = 0; j < 8; j++)
                    acc[i][j] += a[i] * b[j];
        }
    }
    float bj[8];
#pragma unroll
    for (int j = 0; j < 8; j++) {
        int n = n0 + tx * 8 + j;
        bj[j] = bih[n] + bhh[n];
    }
#pragma unroll
    for (int i = 0; i < 8; i++) {
        float4 v0, v1;
        v0.x = acc[i][0] + bj[0]; v0.y = acc[i][1] + bj[1];
        v0.z = acc[i][2] + bj[2]; v0.w = acc[i][3] + bj[3];
        v1.x = acc[i][4] + bj[4]; v1.y = acc[i][5] + bj[5];
        v1.z = acc[i][6] + bj[6]; v1.w = acc[i][7] + bj[7];
        float* cp = C + (size_t)(m0 + ty * 8 + i) * G4 + n0 + tx * 8;
        *(float4*)(cp + 0) = v0;
        *(float4*)(cp + 4) = v1;
    }
}

// ---------------------------------------------------------------------------
// K2b: sentinel-clear the h0 history region (reuses the dead x buffer).
// ---------------------------------------------------------------------------
__global__ __launch_bounds__(256) void k_clear(u32* __restrict__ p) {
    uint4 v; v.x = SENT; v.y = SENT; v.z = SENT; v.w = SENT;
    ((uint4*)p)[(size_t)blockIdx.x * 256 + threadIdx.x] = v;
}

// ---------------------------------------------------------------------------
// K3: R15 = R14 decoupled scans + ADAPTIVE timed waits (per-WG AIMD).
//
// R14 post-mortem: fixed sleep 2048cy systematically undershoots the real
// store->load visibility RT (~3500-4500cy inferred from per-step 5600cy and
// +380MB retry FETCH). Each miss costs ~1000cy (sleep + full load return).
// R15: per-WG adaptive sleep, units of s_sleep(4)~256cy. Miss detection is
// free: __syncthreads_count(miss) replaces the existing round barrier; the
// returned count is WG-uniform so all threads update slp identically (no
// divergence, no LDS). +3 quanta on any miss, -1 on clean rounds, clamp
// [4,24] -> converges to each WG's ~p80 visibility point within ~100 steps
// and tracks drift. Retries stay paced (S_RETRY); traffic stays ~1
// burst/round (anti-storm invariant from R9/R11/R13).
// ---------------------------------------------------------------------------
__global__ __launch_bounds__(256, 2) void k_scan2(
        const float* __restrict__ xg,     // T x 4096 layer-0 preacts
        const float* __restrict__ Wih1,
        const float* __restrict__ Whh0,
        const float* __restrict__ Whh1,
        const float* __restrict__ bih1,
        const float* __restrict__ bhh1,
        u32* h0hist,                      // [T][1024] h0 stream (sentinel-init)
        u64* sl1,                         // [2][1024] tagged h1 slots
        float* __restrict__ out) {
    const int tid  = threadIdx.x;
    const bool isL0 = (blockIdx.x < 256);
    const int w    = isL0 ? blockIdx.x : (blockIdx.x - 256);
    const int wv   = tid >> 6;            // wave 0..3 == state index s
    const int ln   = tid & 63;            // lane
    const int rs   = tid >> 4;            // row slot 0..15 (s_i = rs>>2 == wv)
    const int ck   = tid & 15;            // k-chunk of 64
    const int g_i  = rs & 3;              // gate
    const int r    = g_i * DM + w * 4 + wv;   // global gate row

    __shared__ uint4 hstA[2][16][9];      // h0 staged (f16), parity dbuf
    __shared__ uint4 hstB[2][16][9];      // h1 staged (f16), parity dbuf (L1)

    const int stc = tid >> 4;             // stage chunk for h[tid*4..+4)
    const int sto = tid & 15;             // u64 index within chunk row

    if (isL0) {
        // ---------------- Layer-0 producer loop ----------------
        uint4 wr0[8];                     // Whh0 row r as f16 pairs (32 VGPR)
        {
            const float4* gw = (const float4*)(Whh0 + (size_t)r * DM + ck * 64);
#pragma unroll
            for (int e = 0; e < 8; e++) {
                float4 a = gw[2 * e], b = gw[2 * e + 1];
                uint4 q;
                q.x = pk2_(a.x, a.y); q.y = pk2_(a.z, a.w);
                q.z = pk2_(b.x, b.y); q.w = pk2_(b.z, b.w);
                wr0[e] = q;
            }
        }
        float c0 = 0.f, h0v = 0.f;
        float xgv = (ck == 0) ? xg[r] : 0.f;
        int slp = SLP_INIT;               // adaptive sleep (256cy units)

        for (int t = 0; t < T_SEQ; t++) {
            const int par = t & 1;
            int miss = 0;
            // stage h0(t-1): zero-gap ring -> adaptive silent wait, ONE burst
            if (t == 0) {
                ((u64*)&hstA[0][stc][0])[sto] = 0ull;
            } else {
                for (int i = 0; i < slp; i++) PAUSE(4);
                const u32* hp = h0hist + (size_t)(t - 1) * DM + tid * 4;
                u32 v0, v1, v2, v3;
                for (;;) {
                    v0 = __hip_atomic_load(hp + 0, __ATOMIC_RELAXED, __HIP_MEMORY_SCOPE_AGENT);
                    v1 = __hip_atomic_load(hp + 1, __ATOMIC_RELAXED, __HIP_MEMORY_SCOPE_AGENT);
                    v2 = __hip_atomic_load(hp + 2, __ATOMIC_RELAXED, __HIP_MEMORY_SCOPE_AGENT);
                    v3 = __hip_atomic_load(hp + 3, __ATOMIC_RELAXED, __HIP_MEMORY_SCOPE_AGENT);
                    if ((v0 != SENT) & (v1 != SENT) & (v2 != SENT) & (v3 != SENT)) break;
                    miss = 1;
                    PAUSE(S_RETRY);       // paced fallback, never unpaced
                }
                u32 q0 = pk2_(__uint_as_float(v0), __uint_as_float(v1));
                u32 q1 = pk2_(__uint_as_float(v2), __uint_as_float(v3));
                ((u64*)&hstA[par][stc][0])[sto] = ((u64)q1 << 32) | q0;
            }
            // barrier + free WG-wide miss reduction -> uniform AIMD update
            int nm = __syncthreads_count(miss);
            slp = (nm > 0) ? ((slp + SLP_UP > SLP_MAX) ? SLP_MAX : slp + SLP_UP)
                           : ((slp - SLP_DN < SLP_MIN) ? SLP_MIN : slp - SLP_DN);

            // dot0: Whh0 row r · h0(t-1), weights in VGPRs
            float acc = 0.f;
#pragma unroll
            for (int e = 0; e < 8; e++)
                acc = dot8a_(wr0[e], hstA[par][ck][e], acc);
#pragma unroll
            for (int m = 1; m <= 8; m <<= 1) acc += __shfl_xor(acc, m, 64);
            if (ck == 0) acc += xgv;      // lanes 0,16,32,48 hold gate preacts

            float pi = __shfl(acc, 0, 64);
            float pf = __shfl(acc, 16, 64);
            float pg = __shfl(acc, 32, 64);
            float po = __shfl(acc, 48, 64);
            if (ln == 0) {
                c0 = sigmoidf_(pf) * c0 + sigmoidf_(pi) * tanhf_(pg);
                h0v = sigmoidf_(po) * tanhf_(c0);
                __hip_atomic_store(h0hist + (size_t)t * DM + w * 4 + wv,
                                   __float_as_uint(h0v),
                                   __ATOMIC_RELAXED, __HIP_MEMORY_SCOPE_AGENT);
            }
            // xg prefetch for t+1 (off the critical chain)
            float xgn = 0.f;
            if (ck == 0 && t + 1 < T_SEQ) xgn = xg[(size_t)(t + 1) * G4 + r];
            xgv = xgn;
        }
        // L0 WGs exit; h0hist persists for L1 consumers.
    } else {
        // ---------------- Layer-1 consumer loop ----------------
        uint4 wi1[8], wh1[8];             // Wih1/Whh1 rows (64 VGPR)
        {
            const float4* ga = (const float4*)(Wih1 + (size_t)r * DM + ck * 64);
            const float4* gb = (const float4*)(Whh1 + (size_t)r * DM + ck * 64);
#pragma unroll
            for (int e = 0; e < 8; e++) {
                float4 a = ga[2 * e], b = ga[2 * e + 1];
                uint4 q;
                q.x = pk2_(a.x, a.y); q.y = pk2_(a.z, a.w);
                q.z = pk2_(b.x, b.y); q.w = pk2_(b.z, b.w);
                wi1[e] = q;
                a = gb[2 * e]; b = gb[2 * e + 1];
                q.x = pk2_(a.x, a.y); q.y = pk2_(a.z, a.w);
                q.z = pk2_(b.x, b.y); q.w = pk2_(b.z, b.w);
                wh1[e] = q;
            }
        }
        float b1s[4] = {0.f, 0.f, 0.f, 0.f};
        if (ln == 0) {
#pragma unroll
            for (int gg = 0; gg < 4; gg++)
                b1s[gg] = bih1[gg * DM + w * 4 + wv] + bhh1[gg * DM + w * 4 + wv];
        }
        float c1 = 0.f, h1v = 0.f;
        int slp = SLP_INIT;               // adaptive sleep for the h1 ring

        for (int t = 0; t < T_SEQ; t++) {
            const int par = t & 1;
            const u32* hp = h0hist + (size_t)t * DM + tid * 4;
            int miss = 0;

            // (a) issue h0hist loads FIRST (L0 leads -> expected hit);
            //     their RT hides under the ring sleep below.
            u32 v0 = __hip_atomic_load(hp + 0, __ATOMIC_RELAXED, __HIP_MEMORY_SCOPE_AGENT);
            u32 v1 = __hip_atomic_load(hp + 1, __ATOMIC_RELAXED, __HIP_MEMORY_SCOPE_AGENT);
            u32 v2 = __hip_atomic_load(hp + 2, __ATOMIC_RELAXED, __HIP_MEMORY_SCOPE_AGENT);
            u32 v3 = __hip_atomic_load(hp + 3, __ATOMIC_RELAXED, __HIP_MEMORY_SCOPE_AGENT);

            // (b) adaptive silent wait for the zero-gap h1 ring
            if (t > 0) { for (int i = 0; i < slp; i++) PAUSE(4); }

            // (c) check/stage h0(t); paced catch-up only if L0 is behind
            while ((v0 == SENT) | (v1 == SENT) | (v2 == SENT) | (v3 == SENT)) {
                PAUSE(S_HIST);
                v0 = __hip_atomic_load(hp + 0, __ATOMIC_RELAXED, __HIP_MEMORY_SCOPE_AGENT);
                v1 = __hip_atomic_load(hp + 1, __ATOMIC_RELAXED, __HIP_MEMORY_SCOPE_AGENT);
                v2 = __hip_atomic_load(hp + 2, __ATOMIC_RELAXED, __HIP_MEMORY_SCOPE_AGENT);
                v3 = __hip_atomic_load(hp + 3, __ATOMIC_RELAXED, __HIP_MEMORY_SCOPE_AGENT);
            }
            {
                u32 q0 = pk2_(__uint_as_float(v0), __uint_as_float(v1));
                u32 q1 = pk2_(__uint_as_float(v2), __uint_as_float(v3));
                ((u64*)&hstA[par][stc][0])[sto] = ((u64)q1 << 32) | q0;
            }

            // (d) stage h1(t-1): ONE burst post-sleep, paced retries fallback
            if (t == 0) {
                ((u64*)&hstB[0][stc][0])[sto] = 0ull;
            } else {
                const u64* p1 = sl1 + (size_t)par * 1024 + tid * 4;
                const u32 want = (u32)t;
                u64 d0, d1, d2, d3;
                for (;;) {
                    d0 = __hip_atomic_load(p1 + 0, __ATOMIC_RELAXED, __HIP_MEMORY_SCOPE_AGENT);
                    d1 = __hip_atomic_load(p1 + 1, __ATOMIC_RELAXED, __HIP_MEMORY_SCOPE_AGENT);
                    d2 = __hip_atomic_load(p1 + 2, __ATOMIC_RELAXED, __HIP_MEMORY_SCOPE_AGENT);
                    d3 = __hip_atomic_load(p1 + 3, __ATOMIC_RELAXED, __HIP_MEMORY_SCOPE_AGENT);
                    bool ok = ((u32)(d0 >> 32) == want) & ((u32)(d1 >> 32) == want) &
                              ((u32)(d2 >> 32) == want) & ((u32)(d3 >> 32) == want);
                    if (ok) break;
                    miss = 1;
                    PAUSE(S_RETRY);
                }
                u32 q0 = pk2_(__uint_as_float((u32)d0), __uint_as_float((u32)d1));
                u32 q1 = pk2_(__uint_as_float((u32)d2), __uint_as_float((u32)d3));
                ((u64*)&hstB[par][stc][0])[sto] = ((u64)q1 << 32) | q0;
            }
            // barrier + free miss reduction -> uniform AIMD update
            int nm = __syncthreads_count(miss);
            slp = (nm > 0) ? ((slp + SLP_UP > SLP_MAX) ? SLP_MAX : slp + SLP_UP)
                           : ((slp - SLP_DN < SLP_MIN) ? SLP_MIN : slp - SLP_DN);

            // dot1: Wih1·h0(t); dot2: Whh1·h1(t-1) — both weights in VGPRs
            float a1 = 0.f, a2 = 0.f;
#pragma unroll
            for (int e = 0; e < 8; e++) {
                a1 = dot8a_(wi1[e], hstA[par][ck][e], a1);
                a2 = dot8a_(wh1[e], hstB[par][ck][e], a2);
            }
#pragma unroll
            for (int m = 1; m <= 8; m <<= 1) {
                a1 += __shfl_xor(a1, m, 64);
                a2 += __shfl_xor(a2, m, 64);
            }
            float pi = __shfl(a1, 0, 64)  + __shfl(a2, 0, 64);
            float pf = __shfl(a1, 16, 64) + __shfl(a2, 16, 64);
            float pg = __shfl(a1, 32, 64) + __shfl(a2, 32, 64);
            float po = __shfl(a1, 48, 64) + __shfl(a2, 48, 64);
            if (ln == 0) {
                pi += b1s[0]; pf += b1s[1]; pg += b1s[2]; po += b1s[3];
                c1 = sigmoidf_(pf) * c1 + sigmoidf_(pi) * tanhf_(pg);
                h1v = sigmoidf_(po) * tanhf_(c1);
                u64 v = ((u64)(u32)(t + 1) << 32) | (u64)__float_as_uint(h1v);
                __hip_atomic_store(sl1 + (size_t)((t + 1) & 1) * 1024 + w * 4 + wv,
                                   v, __ATOMIC_RELAXED, __HIP_MEMORY_SCOPE_AGENT);
            }
            // Hazards (single barrier): hstA/hstB[par] written pre-B(t),
            // read post-B(t); next write to same parity is pre-B(t+2), i.e.
            // after B(t+1) -> ordered after all round-t reads. Ring tag
            // staleness: cross-run finals are 4095/4096, never equal to the
            // wanted small tags before first overwrite (R10 argument).
        }
        if (ln == 0) out[w * 4 + wv] = lrelu_(h1v);   // h1[T-1]
    }
}

// ---------------------------------------------------------------------------
extern "C" void kernel_launch(void* const* d_in, const int* in_sizes, int n_in,
                              void* d_out, int out_size, void* d_ws, size_t ws_size,
                              hipStream_t stream) {
    const float* inp = (const float*)d_in[0];   // 4096 x 64
    const float* W1  = (const float*)d_in[1];   // 1024 x 64
    const float* b1  = (const float*)d_in[2];   // 1024
    const float* Wih = (const float*)d_in[3];   // 2 x 4096 x 1024
    const float* Whh = (const float*)d_in[4];   // 2 x 4096 x 1024
    const float* bih = (const float*)d_in[5];   // 2 x 4096
    const float* bhh = (const float*)d_in[6];   // 2 x 4096
    float* out = (float*)d_out;                 // 1024

    // workspace layout:
    //   x: 4096*1024 f32 (K1 out, K2 in) -> REUSED as h0hist (16 MB) after K2
    //   xg: 4096*4096 f32
    //   sl1: 2*1024 u64
    float* x   = (float*)d_ws;
    float* xg  = x + (size_t)T_SEQ * DM;
    u64*   sl1 = (u64*)(xg + (size_t)T_SEQ * G4);
    u32*   h0hist = (u32*)x;
    (void)in_sizes; (void)n_in; (void)out_size; (void)ws_size;

    // Phase 1: input projection
    k_input<<<dim3(T_SEQ), dim3(256), 0, stream>>>(inp, W1, b1, x);

    // Phase 2: xg = x @ Wih0^T + (bih0+bhh0)
    k_gemm<<<dim3(32, 32), dim3(256), 0, stream>>>(x, Wih, bih, bhh, xg);

    // Phase 2b: x is now dead -> sentinel-clear it as the h0 history
    k_clear<<<dim3(4096), dim3(256), 0, stream>>>(h0hist);

    // Phase 3: decoupled layer scans, adaptive timed waits (256 L0 + 256 L1)
    k_scan2<<<dim3(512), dim3(256), 0, stream>>>(
        xg, Wih + LSTRIDE_W, Whh, Whh + LSTRIDE_W,
        bih + LSTRIDE_B, bhh + LSTRIDE_B, h0hist, sl1, out);
}

// Round 6
// 13358.524 us; speedup vs baseline: 1.2540x; 1.2540x over previous
//
#include <hip/hip_runtime.h>
#include <hip/hip_fp16.h>
#include <math.h>

// Problem dims (fixed)
#define T_SEQ 4096
#define DIN   64
#define DM    1024
#define G4    4096              // 4*DM gate rows
#define LSTRIDE_W ((size_t)G4 * DM)   // per-layer Wih/Whh stride
#define LSTRIDE_B ((size_t)G4)        // per-layer bias stride

#define SENT16 0xDEADu          // f16 sentinel: |h|<=1 can never encode 0xDEAD
#define SENT32 0xDEADDEADu

// Fixed timed waits (R15 lesson: adaptive pacing in a globally-coupled ring
// is unstable; fixed uniform pacing is the stable operating point).
#define S_RING  40              // s_sleep(40) ~2560 cy: ring visibility wait
#define S_RETRY 6               // ~384 cy paced retry
#define S_HIST  8               // ~512 cy: L1 catch-up when L0 is behind

typedef unsigned long long u64;
typedef unsigned int u32;
typedef unsigned short u16;

// sleep + compiler memory fence (prevent hoisting atomic loads above it)
#define PAUSE(n) do { __builtin_amdgcn_s_sleep(n); asm volatile("" ::: "memory"); } while (0)

__device__ __forceinline__ float sigmoidf_(float x) {
    return 1.0f / (1.0f + __expf(-x));
}
__device__ __forceinline__ float tanhf_(float x) {
    float ax = fabsf(x);
    float e  = __expf(-2.0f * ax);
    float t  = (1.0f - e) / (1.0f + e);
    return copysignf(t, x);
}
__device__ __forceinline__ float lrelu_(float x) {
    return x > 0.0f ? x : 0.01f * x;
}

// pack two fp32 -> one u32 of two f16 (v_cvt_pkrtz_f16_f32)
__device__ __forceinline__ u32 pk2_(float x, float y) {
    typedef __fp16 hv2 __attribute__((ext_vector_type(2)));
    union { hv2 h; u32 u; } c;
    c.h = __builtin_amdgcn_cvt_pkrtz(x, y);
    return c.u;
}
// fused f16-pair dot-accumulate: acc += a.x*b.x + a.y*b.y
#if __has_builtin(__builtin_amdgcn_fdot2)
__device__ __forceinline__ float d2a_(u32 a, u32 b, float acc) {
    typedef __fp16 hv2 __attribute__((ext_vector_type(2)));
    union { u32 u; hv2 h; } ua, ub;
    ua.u = a; ub.u = b;
    return __builtin_amdgcn_fdot2(ua.h, ub.h, acc, false);
}
#else
__device__ __forceinline__ float d2a_(u32 a, u32 b, float acc) {
    union { u32 u; __half2 h; } ua, ub;
    ua.u = a; ub.u = b;
    float2 fa = __half22float2(ua.h);
    float2 fb = __half22float2(ub.h);
    return acc + fa.x * fb.x + fa.y * fb.y;
}
#endif
__device__ __forceinline__ float dot8a_(uint4 q, uint4 h, float acc) {
    acc = d2a_(q.x, h.x, acc);
    acc = d2a_(q.y, h.y, acc);
    acc = d2a_(q.z, h.z, acc);
    acc = d2a_(q.w, h.w, acc);
    return acc;
}
// any of the four f16 fields still the sentinel?
__device__ __forceinline__ bool has_sent_(u64 v) {
    return (((u32)v & 0xFFFFu) == SENT16) | ((((u32)v >> 16)) == SENT16) |
           (((u32)(v >> 32) & 0xFFFFu) == SENT16) | (((u32)(v >> 48)) == SENT16);
}

// ---------------------------------------------------------------------------
// K1: x[t,d] = leaky_relu(sum_k inp[t,k]*W1[d,k] + b1[d]);  grid=4096, block=256
// ---------------------------------------------------------------------------
__global__ __launch_bounds__(256) void k_input(const float* __restrict__ inp,
                                               const float* __restrict__ W1,
                                               const float* __restrict__ b1,
                                               float* __restrict__ x) {
    __shared__ float s_in[DIN];
    const int t   = blockIdx.x;
    const int tid = threadIdx.x;
    if (tid < DIN) s_in[tid] = inp[(size_t)t * DIN + tid];
    __syncthreads();
#pragma unroll
    for (int q = 0; q < 4; q++) {
        const int d = tid + q * 256;
        const float4* wr = (const float4*)(W1 + (size_t)d * DIN);
        float acc = 0.0f;
#pragma unroll
        for (int e = 0; e < 16; e++) {
            float4 w = wr[e];
            acc += w.x * s_in[e * 4 + 0] + w.y * s_in[e * 4 + 1] +
                   w.z * s_in[e * 4 + 2] + w.w * s_in[e * 4 + 3];
        }
        acc += b1[d];
        x[(size_t)t * DM + d] = lrelu_(acc);
    }
}

// ---------------------------------------------------------------------------
// K2: xg[m,n] = sum_k x[m,k]*Wih0[n,k] + (bih0[n]+bhh0[n])
// 128x128 tile, BK=16, 256 threads, 8x8 per thread.
// ---------------------------------------------------------------------------
__global__ __launch_bounds__(256) void k_gemm(const float* __restrict__ A,
                                              const float* __restrict__ B,
                                              const float* __restrict__ bih,
                                              const float* __restrict__ bhh,
                                              float* __restrict__ C) {
    const int K = DM;
    __shared__ float As[16][132];
    __shared__ float Bs[16][132];
    const int tid = threadIdx.x;
    const int m0 = blockIdx.y * 128, n0 = blockIdx.x * 128;
    const int tx = tid & 15, ty = tid >> 4;
    const int lr = tid >> 1;
    const int lc = (tid & 1) * 8;

    float acc[8][8] = {};
    const float4* ag = (const float4*)(A + (size_t)(m0 + lr) * K + lc);
    const float4* bg = (const float4*)(B + (size_t)(n0 + lr) * K + lc);

    for (int k0 = 0; k0 < K; k0 += 16) {
        float4 a0 = ag[0], a1 = ag[1];
        float4 b0 = bg[0], b1v = bg[1];
        ag += 4; bg += 4;
        __syncthreads();
        As[lc + 0][lr] = a0.x; As[lc + 1][lr] = a0.y; As[lc + 2][lr] = a0.z; As[lc + 3][lr] = a0.w;
        As[lc + 4][lr] = a1.x; As[lc + 5][lr] = a1.y; As[lc + 6][lr] = a1.z; As[lc + 7][lr] = a1.w;
        Bs[lc + 0][lr] = b0.x; Bs[lc + 1][lr] = b0.y; Bs[lc + 2][lr] = b0.z; Bs[lc + 3][lr] = b0.w;
        Bs[lc + 4][lr] = b1v.x; Bs[lc + 5][lr] = b1v.y; Bs[lc + 6][lr] = b1v.z; Bs[lc + 7][lr] = b1v.w;
        __syncthreads();
#pragma unroll
        for (int k = 0; k < 16; k++) {
            float a[8], b[8];
            *(float4*)&a[0] = *(const float4*)&As[k][ty * 8 + 0];
            *(float4*)&a[4] = *(const float4*)&As[k][ty * 8 + 4];
            *(float4*)&b[0] = *(const float4*)&Bs[k][tx * 8 + 0];
            *(float4*)&b[4] = *(const float4*)&Bs[k][tx * 8 + 4];
#pragma unroll
            for (int i = 0; i < 8; i++)
#pragma unroll
                for (int j = 0; j < 8; j++)
                    acc[i][j] += a[i] * b[j];
        }
    }
    float bj[8];
#pragma unroll
    for (int j = 0; j < 8; j++) {
        int n = n0 + tx * 8 + j;
        bj[j] = bih[n] + bhh[n];
    }
#pragma unroll
    for (int i = 0; i < 8; i++) {
        float4 v0, v1;
        v0.x = acc[i][0] + bj[0]; v0.y = acc[i][1] + bj[1];
        v0.z = acc[i][2] + bj[2]; v0.w = acc[i][3] + bj[3];
        v1.x = acc[i][4] + bj[4]; v1.y = acc[i][5] + bj[5];
        v1.z = acc[i][6] + bj[6]; v1.w = acc[i][7] + bj[7];
        float* cp = C + (size_t)(m0 + ty * 8 + i) * G4 + n0 + tx * 8;
        *(float4*)(cp + 0) = v0;
        *(float4*)(cp + 4) = v1;
    }
}

// ---------------------------------------------------------------------------
// K2b: sentinel-clear BOTH f16 histories (16 MB over the dead x buffer).
// ---------------------------------------------------------------------------
__global__ __launch_bounds__(256) void k_clear(u32* __restrict__ p) {
    uint4 v; v.x = SENT32; v.y = SENT32; v.z = SENT32; v.w = SENT32;
    ((uint4*)p)[(size_t)blockIdx.x * 256 + threadIdx.x] = v;
}

// ---------------------------------------------------------------------------
// K3: R16 = decoupled scans + FIXED timed waits + f16 sentinel histories.
//
// Evidence ladder:
//  R10 10.77ms: lockstep, 2 serialized RTs/round.  R14 9.63ms: decoupled +
//  fixed sleep 2048cy (stable).  R15 regressed: adaptive pacing in a closed
//  loop diverges (positive feedback to SLP_MAX) -> FIXED pacing only.
// R16 changes vs R14:
//  - h1 ring -> h1hist[T][1024] f16 sentinel history (like h0hist, which
//    also becomes f16). Producer stores ONE u16 (RTZ f16, bit-identical to
//    the consumer-side conversion it replaces). Consumer: ONE u64 load per
//    thread (was 4), staged into LDS verbatim (no tags, no pk2). Write-once
//    rows: no ABA, no parity protocol. Burst bytes: h0 4->2KB, h1 8->2KB.
//  - sleep 2048 -> 2560cy (R14 miss evidence: visibility ~3000-3500cy).
//  - parallel gate activations on lanes 0/16/32/48 (was 5 serial
//    transcendentals on lane0) -> shorter publish path, less skew.
//  - L1: h1 load issued pre-B1, RT hides under B1+dot1, checked before dot2.
// ---------------------------------------------------------------------------
__global__ __launch_bounds__(256, 2) void k_scan2(
        const float* __restrict__ xg,     // T x 4096 layer-0 preacts
        const float* __restrict__ Wih1,
        const float* __restrict__ Whh0,
        const float* __restrict__ Whh1,
        const float* __restrict__ bih1,
        const float* __restrict__ bhh1,
        u16* h0h,                         // [T][1024] f16 h0 history (sentinel)
        u16* h1h,                         // [T][1024] f16 h1 history (sentinel)
        float* __restrict__ out) {
    const int tid  = threadIdx.x;
    const bool isL0 = (blockIdx.x < 256);
    const int w    = isL0 ? blockIdx.x : (blockIdx.x - 256);
    const int wv   = tid >> 6;            // wave 0..3 == state index s
    const int ln   = tid & 63;            // lane
    const int rs   = tid >> 4;            // row slot 0..15
    const int ck   = tid & 15;            // k-chunk of 64
    const int g_i  = rs & 3;              // gate (0=i,1=f,2=g,3=o)
    const int r    = g_i * DM + w * 4 + wv;   // global gate row

    __shared__ uint4 hstA[2][16][9];      // h0 staged (f16), parity dbuf
    __shared__ uint4 hstB[2][16][9];      // h1 staged (f16), parity dbuf (L1)

    // thread tid stages states [4*tid, 4*tid+4) as one u64:
    const int stc = tid >> 4;             // LDS row (64 states)
    const int sto = tid & 15;             // u64 slot within row

    if (isL0) {
        // ---------------- Layer-0 producer loop ----------------
        uint4 wr0[8];                     // Whh0 row r as f16 pairs (32 VGPR)
        {
            const float4* gw = (const float4*)(Whh0 + (size_t)r * DM + ck * 64);
#pragma unroll
            for (int e = 0; e < 8; e++) {
                float4 a = gw[2 * e], b = gw[2 * e + 1];
                uint4 q;
                q.x = pk2_(a.x, a.y); q.y = pk2_(a.z, a.w);
                q.z = pk2_(b.x, b.y); q.w = pk2_(b.z, b.w);
                wr0[e] = q;
            }
        }
        float c0 = 0.f, h0v = 0.f;
        float xgv = (ck == 0) ? xg[r] : 0.f;

        for (int t = 0; t < T_SEQ; t++) {
            const int par = t & 1;
            // stage h0(t-1): zero-gap -> fixed silent wait, then ONE u64 load
            if (t == 0) {
                ((u64*)&hstA[0][stc][0])[sto] = 0ull;
            } else {
                PAUSE(S_RING);
                const u64* hp = (const u64*)(h0h + (size_t)(t - 1) * DM) + tid;
                u64 v;
                for (;;) {
                    v = __hip_atomic_load(hp, __ATOMIC_RELAXED, __HIP_MEMORY_SCOPE_AGENT);
                    if (!has_sent_(v)) break;
                    PAUSE(S_RETRY);       // paced fallback, never unpaced
                }
                ((u64*)&hstA[par][stc][0])[sto] = v;
            }
            __syncthreads();              // the ONLY barrier per L0 round

            // dot0: Whh0 row r · h0(t-1), weights in VGPRs
            float acc = 0.f;
#pragma unroll
            for (int e = 0; e < 8; e++)
                acc = dot8a_(wr0[e], hstA[par][ck][e], acc);
#pragma unroll
            for (int m = 1; m <= 8; m <<= 1) acc += __shfl_xor(acc, m, 64);
            if (ck == 0) acc += xgv;      // lanes 0,16,32,48 hold gate preacts

            // parallel activations: each leader lane applies ITS gate's fn
            float act = ((ln >> 4) == 2) ? tanhf_(acc) : sigmoidf_(acc);
            float ai = __shfl(act, 0, 64);
            float af = __shfl(act, 16, 64);
            float ag = __shfl(act, 32, 64);
            float ao = __shfl(act, 48, 64);
            if (ln == 0) {
                c0  = af * c0 + ai * ag;
                h0v = ao * tanhf_(c0);
                u32 q = pk2_(h0v, h0v);   // RTZ f16, same bits as old consumer
                __hip_atomic_store(h0h + (size_t)t * DM + w * 4 + wv, (u16)(q & 0xFFFFu),
                                   __ATOMIC_RELAXED, __HIP_MEMORY_SCOPE_AGENT);
            }
            // xg prefetch for t+1 (off the critical chain)
            float xgn = 0.f;
            if (ck == 0 && t + 1 < T_SEQ) xgn = xg[(size_t)(t + 1) * G4 + r];
            xgv = xgn;
        }
        // L0 WGs exit; h0h persists for L1 consumers.
    } else {
        // ---------------- Layer-1 consumer loop ----------------
        uint4 wi1[8], wh1[8];             // Wih1/Whh1 rows (64 VGPR)
        {
            const float4* ga = (const float4*)(Wih1 + (size_t)r * DM + ck * 64);
            const float4* gb = (const float4*)(Whh1 + (size_t)r * DM + ck * 64);
#pragma unroll
            for (int e = 0; e < 8; e++) {
                float4 a = ga[2 * e], b = ga[2 * e + 1];
                uint4 q;
                q.x = pk2_(a.x, a.y); q.y = pk2_(a.z, a.w);
                q.z = pk2_(b.x, b.y); q.w = pk2_(b.z, b.w);
                wi1[e] = q;
                a = gb[2 * e]; b = gb[2 * e + 1];
                q.x = pk2_(a.x, a.y); q.y = pk2_(a.z, a.w);
                q.z = pk2_(b.x, b.y); q.w = pk2_(b.z, b.w);
                wh1[e] = q;
            }
        }
        // per-leader-lane gate bias (lane ln = 16*g holds gate g's bias)
        float bsel = 0.f;
        if ((ln & 15) == 0) {
            const int gg = ln >> 4;
            bsel = bih1[gg * DM + w * 4 + wv] + bhh1[gg * DM + w * 4 + wv];
        }
        float c1 = 0.f, h1v = 0.f;

        for (int t = 0; t < T_SEQ; t++) {
            const int par = t & 1;
            const u64* hp0 = (const u64*)(h0h + (size_t)t * DM) + tid;
            const u64* hp1 = (const u64*)(h1h + (size_t)(t > 0 ? t - 1 : 0) * DM) + tid;

            // (a) pre-issue h0(t) load (L0 leads -> expected hit; RT hides
            //     under the ring sleep)
            u64 v0 = __hip_atomic_load(hp0, __ATOMIC_RELAXED, __HIP_MEMORY_SCOPE_AGENT);

            // (b) fixed silent wait for the zero-gap h1 history
            if (t > 0) PAUSE(S_RING);

            // (c) check/stage h0(t); paced catch-up only if L0 is behind
            while (has_sent_(v0)) {
                PAUSE(S_HIST);
                v0 = __hip_atomic_load(hp0, __ATOMIC_RELAXED, __HIP_MEMORY_SCOPE_AGENT);
            }
            ((u64*)&hstA[par][stc][0])[sto] = v0;

            // (d) issue h1(t-1) load now; its RT hides under B1 + dot1
            u64 v1 = 0;
            if (t > 0)
                v1 = __hip_atomic_load(hp1, __ATOMIC_RELAXED, __HIP_MEMORY_SCOPE_AGENT);
            __syncthreads();              // B1: hstA[par] visible

            // dot1: Wih1 · h0(t)
            float a1 = 0.f;
#pragma unroll
            for (int e = 0; e < 8; e++)
                a1 = dot8a_(wi1[e], hstA[par][ck][e], a1);
#pragma unroll
            for (int m = 1; m <= 8; m <<= 1) a1 += __shfl_xor(a1, m, 64);

            // (e) check/stage h1(t-1)
            if (t == 0) {
                ((u64*)&hstB[0][stc][0])[sto] = 0ull;
            } else {
                while (has_sent_(v1)) {
                    PAUSE(S_RETRY);
                    v1 = __hip_atomic_load(hp1, __ATOMIC_RELAXED, __HIP_MEMORY_SCOPE_AGENT);
                }
                ((u64*)&hstB[par][stc][0])[sto] = v1;
            }
            __syncthreads();              // B2: hstB[par] visible

            // dot2: Whh1 · h1(t-1)
            float a2 = 0.f;
#pragma unroll
            for (int e = 0; e < 8; e++)
                a2 = dot8a_(wh1[e], hstB[par][ck][e], a2);
#pragma unroll
            for (int m = 1; m <= 8; m <<= 1) a2 += __shfl_xor(a2, m, 64);

            // parallel activations on leader lanes (preact = a1 + a2 + bias)
            float p = (a1 + a2) + bsel;
            float act = ((ln >> 4) == 2) ? tanhf_(p) : sigmoidf_(p);
            float ai = __shfl(act, 0, 64);
            float af = __shfl(act, 16, 64);
            float ag = __shfl(act, 32, 64);
            float ao = __shfl(act, 48, 64);
            if (ln == 0) {
                c1  = af * c1 + ai * ag;
                h1v = ao * tanhf_(c1);
                u32 q = pk2_(h1v, h1v);
                __hip_atomic_store(h1h + (size_t)t * DM + w * 4 + wv, (u16)(q & 0xFFFFu),
                                   __ATOMIC_RELAXED, __HIP_MEMORY_SCOPE_AGENT);
            }
            // Hazards: hstA[par] write pre-B1(t), read dot1 post-B1(t); next
            // same-parity write is pre-B1(t+2) > B1(t+1) > all round-t reads.
            // hstB[par] write pre-B2(t), read dot2 post-B2(t); same argument.
            // Histories are write-once rows: no reuse hazards, no tags.
        }
        if (ln == 0) out[w * 4 + wv] = lrelu_(h1v);   // h1[T-1]
    }
}

// ---------------------------------------------------------------------------
extern "C" void kernel_launch(void* const* d_in, const int* in_sizes, int n_in,
                              void* d_out, int out_size, void* d_ws, size_t ws_size,
                              hipStream_t stream) {
    const float* inp = (const float*)d_in[0];   // 4096 x 64
    const float* W1  = (const float*)d_in[1];   // 1024 x 64
    const float* b1  = (const float*)d_in[2];   // 1024
    const float* Wih = (const float*)d_in[3];   // 2 x 4096 x 1024
    const float* Whh = (const float*)d_in[4];   // 2 x 4096 x 1024
    const float* bih = (const float*)d_in[5];   // 2 x 4096
    const float* bhh = (const float*)d_in[6];   // 2 x 4096
    float* out = (float*)d_out;                 // 1024

    // workspace layout (80 MB, unchanged footprint):
    //   x: 4096*1024 f32 (16 MB; K1 out, K2 in) -> dead after K2, REUSED as
    //      h0h (8 MB f16) + h1h (8 MB f16) sentinel histories
    //   xg: 4096*4096 f32 (64 MB)
    float* x   = (float*)d_ws;
    float* xg  = x + (size_t)T_SEQ * DM;
    u16*   h0h = (u16*)d_ws;
    u16*   h1h = (u16*)d_ws + (size_t)T_SEQ * DM;
    (void)in_sizes; (void)n_in; (void)out_size; (void)ws_size;

    // Phase 1: input projection
    k_input<<<dim3(T_SEQ), dim3(256), 0, stream>>>(inp, W1, b1, x);

    // Phase 2: xg = x @ Wih0^T + (bih0+bhh0)
    k_gemm<<<dim3(32, 32), dim3(256), 0, stream>>>(x, Wih, bih, bhh, xg);

    // Phase 2b: x is dead -> sentinel-clear both histories (16 MB)
    k_clear<<<dim3(4096), dim3(256), 0, stream>>>((u32*)d_ws);

    // Phase 3: decoupled layer scans, fixed timed waits (256 L0 + 256 L1)
    k_scan2<<<dim3(512), dim3(256), 0, stream>>>(
        xg, Wih + LSTRIDE_W, Whh, Whh + LSTRIDE_W,
        bih + LSTRIDE_B, bhh + LSTRIDE_B, h0h, h1h, out);
}

// Round 7
// 8873.606 us; speedup vs baseline: 1.8877x; 1.5054x over previous
//
#include <hip/hip_runtime.h>
#include <hip/hip_fp16.h>
#include <math.h>

// Problem dims (fixed)
#define T_SEQ 4096
#define DIN   64
#define DM    1024
#define G4    4096              // 4*DM gate rows
#define LSTRIDE_W ((size_t)G4 * DM)   // per-layer Wih/Whh stride
#define LSTRIDE_B ((size_t)G4)        // per-layer bias stride

#define SENT16 0xDEADu          // f16 sentinel: |h|<=1 never encodes 0xDEAD
#define SENT32 0xDEADDEADu

// Fixed timed waits (R15: adaptive pacing diverges in a coupled ring; fixed
// uniform pacing is the stable operating point).
#define S_RING  28              // s_sleep(28) ~1792 cy: ring visibility wait
#define S_RETRY 6               // ~384 cy paced retry
#define S_HIST  8               // ~512 cy: L1 catch-up when L0 is behind

typedef unsigned long long u64;
typedef unsigned int u32;
typedef unsigned short u16;

// sleep + compiler memory fence (prevent hoisting atomic loads above it)
#define PAUSE(n) do { __builtin_amdgcn_s_sleep(n); asm volatile("" ::: "memory"); } while (0)

__device__ __forceinline__ float sigmoidf_(float x) {
    return 1.0f / (1.0f + __expf(-x));
}
__device__ __forceinline__ float tanhf_(float x) {
    float ax = fabsf(x);
    float e  = __expf(-2.0f * ax);
    float t  = (1.0f - e) / (1.0f + e);
    return copysignf(t, x);
}
__device__ __forceinline__ float lrelu_(float x) {
    return x > 0.0f ? x : 0.01f * x;
}

// pack two fp32 -> one u32 of two f16 (v_cvt_pkrtz_f16_f32)
__device__ __forceinline__ u32 pk2_(float x, float y) {
    typedef __fp16 hv2 __attribute__((ext_vector_type(2)));
    union { hv2 h; u32 u; } c;
    c.h = __builtin_amdgcn_cvt_pkrtz(x, y);
    return c.u;
}
// fused f16-pair dot-accumulate: acc += a.x*b.x + a.y*b.y
#if __has_builtin(__builtin_amdgcn_fdot2)
__device__ __forceinline__ float d2a_(u32 a, u32 b, float acc) {
    typedef __fp16 hv2 __attribute__((ext_vector_type(2)));
    union { u32 u; hv2 h; } ua, ub;
    ua.u = a; ub.u = b;
    return __builtin_amdgcn_fdot2(ua.h, ub.h, acc, false);
}
#else
__device__ __forceinline__ float d2a_(u32 a, u32 b, float acc) {
    union { u32 u; __half2 h; } ua, ub;
    ua.u = a; ub.u = b;
    float2 fa = __half22float2(ua.h);
    float2 fb = __half22float2(ub.h);
    return acc + fa.x * fb.x + fa.y * fb.y;
}
#endif
__device__ __forceinline__ float dot8a_(uint4 q, uint4 h, float acc) {
    acc = d2a_(q.x, h.x, acc);
    acc = d2a_(q.y, h.y, acc);
    acc = d2a_(q.z, h.z, acc);
    acc = d2a_(q.w, h.w, acc);
    return acc;
}
// any of the four f16 fields still the sentinel?
__device__ __forceinline__ bool has_sent_(u64 v) {
    return (((u32)v & 0xFFFFu) == SENT16) | ((((u32)v >> 16)) == SENT16) |
           (((u32)(v >> 32) & 0xFFFFu) == SENT16) | (((u32)(v >> 48)) == SENT16);
}

// ---------------------------------------------------------------------------
// K1: x[t,d] = leaky_relu(sum_k inp[t,k]*W1[d,k] + b1[d]);  grid=4096, block=256
// ---------------------------------------------------------------------------
__global__ __launch_bounds__(256) void k_input(const float* __restrict__ inp,
                                               const float* __restrict__ W1,
                                               const float* __restrict__ b1,
                                               float* __restrict__ x) {
    __shared__ float s_in[DIN];
    const int t   = blockIdx.x;
    const int tid = threadIdx.x;
    if (tid < DIN) s_in[tid] = inp[(size_t)t * DIN + tid];
    __syncthreads();
#pragma unroll
    for (int q = 0; q < 4; q++) {
        const int d = tid + q * 256;
        const float4* wr = (const float4*)(W1 + (size_t)d * DIN);
        float acc = 0.0f;
#pragma unroll
        for (int e = 0; e < 16; e++) {
            float4 w = wr[e];
            acc += w.x * s_in[e * 4 + 0] + w.y * s_in[e * 4 + 1] +
                   w.z * s_in[e * 4 + 2] + w.w * s_in[e * 4 + 3];
        }
        acc += b1[d];
        x[(size_t)t * DM + d] = lrelu_(acc);
    }
}

// ---------------------------------------------------------------------------
// K2: xg[m,n] = sum_k x[m,k]*Wih0[n,k] + (bih0[n]+bhh0[n])
// 128x128 tile, BK=16, 256 threads, 8x8 per thread.
// ---------------------------------------------------------------------------
__global__ __launch_bounds__(256) void k_gemm(const float* __restrict__ A,
                                              const float* __restrict__ B,
                                              const float* __restrict__ bih,
                                              const float* __restrict__ bhh,
                                              float* __restrict__ C) {
    const int K = DM;
    __shared__ float As[16][132];
    __shared__ float Bs[16][132];
    const int tid = threadIdx.x;
    const int m0 = blockIdx.y * 128, n0 = blockIdx.x * 128;
    const int tx = tid & 15, ty = tid >> 4;
    const int lr = tid >> 1;
    const int lc = (tid & 1) * 8;

    float acc[8][8] = {};
    const float4* ag = (const float4*)(A + (size_t)(m0 + lr) * K + lc);
    const float4* bg = (const float4*)(B + (size_t)(n0 + lr) * K + lc);

    for (int k0 = 0; k0 < K; k0 += 16) {
        float4 a0 = ag[0], a1 = ag[1];
        float4 b0 = bg[0], b1v = bg[1];
        ag += 4; bg += 4;
        __syncthreads();
        As[lc + 0][lr] = a0.x; As[lc + 1][lr] = a0.y; As[lc + 2][lr] = a0.z; As[lc + 3][lr] = a0.w;
        As[lc + 4][lr] = a1.x; As[lc + 5][lr] = a1.y; As[lc + 6][lr] = a1.z; As[lc + 7][lr] = a1.w;
        Bs[lc + 0][lr] = b0.x; Bs[lc + 1][lr] = b0.y; Bs[lc + 2][lr] = b0.z; Bs[lc + 3][lr] = b0.w;
        Bs[lc + 4][lr] = b1v.x; Bs[lc + 5][lr] = b1v.y; Bs[lc + 6][lr] = b1v.z; Bs[lc + 7][lr] = b1v.w;
        __syncthreads();
#pragma unroll
        for (int k = 0; k < 16; k++) {
            float a[8], b[8];
            *(float4*)&a[0] = *(const float4*)&As[k][ty * 8 + 0];
            *(float4*)&a[4] = *(const float4*)&As[k][ty * 8 + 4];
            *(float4*)&b[0] = *(const float4*)&Bs[k][tx * 8 + 0];
            *(float4*)&b[4] = *(const float4*)&Bs[k][tx * 8 + 4];
#pragma unroll
            for (int i = 0; i < 8; i++)
#pragma unroll
                for (int j = 0; j < 8; j++)
                    acc[i][j] += a[i] * b[j];
        }
    }
    float bj[8];
#pragma unroll
    for (int j = 0; j < 8; j++) {
        int n = n0 + tx * 8 + j;
        bj[j] = bih[n] + bhh[n];
    }
#pragma unroll
    for (int i = 0; i < 8; i++) {
        float4 v0, v1;
        v0.x = acc[i][0] + bj[0]; v0.y = acc[i][1] + bj[1];
        v0.z = acc[i][2] + bj[2]; v0.w = acc[i][3] + bj[3];
        v1.x = acc[i][4] + bj[4]; v1.y = acc[i][5] + bj[5];
        v1.z = acc[i][6] + bj[6]; v1.w = acc[i][7] + bj[7];
        float* cp = C + (size_t)(m0 + ty * 8 + i) * G4 + n0 + tx * 8;
        *(float4*)(cp + 0) = v0;
        *(float4*)(cp + 4) = v1;
    }
}

// ---------------------------------------------------------------------------
// K2b: sentinel-clear BOTH f16 histories (16 MB over the dead x buffer).
// ---------------------------------------------------------------------------
__global__ __launch_bounds__(256) void k_clear(u32* __restrict__ p) {
    uint4 v; v.x = SENT32; v.y = SENT32; v.z = SENT32; v.w = SENT32;
    ((uint4*)p)[(size_t)blockIdx.x * 256 + threadIdx.x] = v;
}

// ---------------------------------------------------------------------------
// K3: R17 = coarse-granularity decoupled scans.
//
// Measured invariant (R10/R14/R16): period = sleep + ~3900cy, dominated by
// store->load MALL visibility as seen by the slowest of 256 fragmented
// publishers (4 scattered u16 stores each, un-coalescable across CUs).
// R17 attacks the topology:
//   - 32 L0 WGs x 32 states, 64 L1 WGs x 16 states, 1024 threads each.
//   - ALL states of a WG are computed on wave-0 lanes -> the publish is ONE
//     wave-coalesced store instruction = single 64B/32B MALL transaction.
//     32 publishers instead of 256; straggler max over 32, not 256.
//   - 96 polling WGs instead of 512.
//   - compute: 128 rows/WG, 8 threads/row (128 MACs, 64 VGPR weights),
//     shfl_xor reduce, LDS gather via pre[] for gate math.
// Ring protocol per R14/R16 (proven): fixed silent sleep -> one burst ->
// paced retries; L1 h0-read load-first with paced catch-up; write-once f16
// sentinel histories (no tags, no ABA).
// ---------------------------------------------------------------------------
__global__ __launch_bounds__(1024, 1) void k_scan(
        const float* __restrict__ xg,     // T x 4096 layer-0 preacts
        const float* __restrict__ Wih1,
        const float* __restrict__ Whh0,
        const float* __restrict__ Whh1,
        const float* __restrict__ bih1,
        const float* __restrict__ bhh1,
        u16* h0h,                         // [T][1024] f16 h0 history (sentinel)
        u16* h1h,                         // [T][1024] f16 h1 history (sentinel)
        float* __restrict__ out) {
    const int tid   = threadIdx.x;
    const int rowid = tid >> 3;           // 0..127: row handled by this thread
    const int c     = tid & 7;            // k-chunk within row
    const bool isL0 = (blockIdx.x < 32);

    __shared__ uint4 h0st[2][128];        // staged h0 row (f16), parity dbuf
    __shared__ uint4 h1st[2][128];        // staged h1 row (f16), parity dbuf
    __shared__ __align__(16) float pre[128];  // row preacts for gate gather

    if (isL0) {
        // =============== Layer-0: 32 WGs x 32 states ===============
        const int w = blockIdx.x;                 // states [32w, 32w+32)
        const int g = rowid & 3, s = rowid >> 2;  // pre[4s+g] layout
        const int rg = g * DM + 32 * w + s;       // row in Whh0 / xg column
        // weights: W[rg, 8c+64j .. +8), j=0..15  (k-interleave: LDS reads at
        // byte 16c+128j are bank-conflict-free across the 8 row threads)
        uint4 wq[16];
#pragma unroll
        for (int j = 0; j < 16; j++) {
            const float4* p = (const float4*)(Whh0 + (size_t)rg * DM + 8 * c + 64 * j);
            float4 a = p[0], b = p[1];
            wq[j].x = pk2_(a.x, a.y); wq[j].y = pk2_(a.z, a.w);
            wq[j].z = pk2_(b.x, b.y); wq[j].w = pk2_(b.z, b.w);
        }
        const bool stg = (tid >= 64 && tid < 320);  // stagers: waves 1-4
        const int  slot = tid - 64;                 // u64 slot 0..255
        const bool ldr = (c == 0);                  // row leader
        const bool pub = (tid < 32);                // wave-0 publisher lanes
        float c0 = 0.f, h0v = 0.f;

        for (int t = 0; t < T_SEQ; t++) {
            const int par = t & 1;
            float xgv = 0.f;
            if (ldr) xgv = xg[(size_t)t * G4 + rg];   // RT hides under stage+B1

            if (t == 0) {
                if (stg) ((u64*)&h0st[0][0])[slot] = 0ull;
            } else if (stg) {
                PAUSE(S_RING);            // silent visibility wait
                const u64* hp = (const u64*)(h0h + (size_t)(t - 1) * DM) + slot;
                u64 v;
                for (;;) {
                    v = __hip_atomic_load(hp, __ATOMIC_RELAXED, __HIP_MEMORY_SCOPE_AGENT);
                    if (!has_sent_(v)) break;
                    PAUSE(S_RETRY);       // paced fallback, never unpaced
                }
                ((u64*)&h0st[par][0])[slot] = v;
            }
            __syncthreads();              // B1: h0st[par] staged

            // dot: row rg · h0(t-1); weights VGPR, vector from LDS
            const uint4* hb = &h0st[par][0];
            float acc = 0.f;
#pragma unroll
            for (int j = 0; j < 16; j++)
                acc = dot8a_(wq[j], hb[c + 8 * j], acc);
            acc += __shfl_xor(acc, 1, 64);
            acc += __shfl_xor(acc, 2, 64);
            acc += __shfl_xor(acc, 4, 64);
            if (ldr) pre[rowid] = acc + xgv;
            __syncthreads();              // B2: pre[] complete

            if (pub) {                    // wave-0 lane tid = state tid
                float4 p4 = *(const float4*)&pre[4 * tid];   // i,f,g,o preacts
                float i_ = sigmoidf_(p4.x), f_ = sigmoidf_(p4.y);
                float g_ = tanhf_(p4.z),   o_ = sigmoidf_(p4.w);
                c0  = f_ * c0 + i_ * g_;
                h0v = o_ * tanhf_(c0);
                u32 q = pk2_(h0v, h0v);   // RTZ f16
                // 32 consecutive lanes -> ONE coalesced 64B line store
                __hip_atomic_store(h0h + (size_t)t * DM + 32 * w + tid,
                                   (u16)(q & 0xFFFFu),
                                   __ATOMIC_RELAXED, __HIP_MEMORY_SCOPE_AGENT);
            }
        }
    } else {
        // =============== Layer-1: 64 WGs x 16 states ===============
        const int u = blockIdx.x - 32;              // states [16u, 16u+16)
        const int g = rowid & 3;                    // gate
        const int m = (rowid >> 2) & 1;             // 0=Wih1(h0), 1=Whh1(h1)
        const int s = rowid >> 3;                   // state 0..15
        const float* WB = m ? Whh1 : Wih1;
        const int rg = g * DM + 16 * u + s;         // row within matrix
        uint4 wq[16];
#pragma unroll
        for (int j = 0; j < 16; j++) {
            const float4* p = (const float4*)(WB + (size_t)rg * DM + 8 * c + 64 * j);
            float4 a = p[0], b = p[1];
            wq[j].x = pk2_(a.x, a.y); wq[j].y = pk2_(a.z, a.w);
            wq[j].z = pk2_(b.x, b.y); wq[j].w = pk2_(b.z, b.w);
        }
        float bsum[4] = {0.f, 0.f, 0.f, 0.f};
        if (tid < 16) {
#pragma unroll
            for (int gg = 0; gg < 4; gg++)
                bsum[gg] = bih1[gg * DM + 16 * u + tid] + bhh1[gg * DM + 16 * u + tid];
        }
        const bool st0 = (tid >= 64 && tid < 320);   // h0 stagers
        const int  sl0 = tid - 64;
        const bool st1 = (tid >= 320 && tid < 576);  // h1 stagers
        const int  sl1 = tid - 320;
        const bool ldr = (c == 0);
        const bool pub = (tid < 16);
        float c1 = 0.f, h1v = 0.f;

        for (int t = 0; t < T_SEQ; t++) {
            const int par = t & 1;

            // h0(t): load-first (L0 leads in steady state), paced catch-up.
            if (st0) {
                const u64* hp = (const u64*)(h0h + (size_t)t * DM) + sl0;
                u64 v = __hip_atomic_load(hp, __ATOMIC_RELAXED, __HIP_MEMORY_SCOPE_AGENT);
                while (has_sent_(v)) {
                    PAUSE(S_HIST);
                    v = __hip_atomic_load(hp, __ATOMIC_RELAXED, __HIP_MEMORY_SCOPE_AGENT);
                }
                ((u64*)&h0st[par][0])[sl0] = v;
            }
            // h1(t-1): zero-gap self-ring -> sleep-first, one burst, paced.
            if (t == 0) {
                if (st1) ((u64*)&h1st[0][0])[sl1] = 0ull;
            } else if (st1) {
                PAUSE(S_RING);
                const u64* hp = (const u64*)(h1h + (size_t)(t - 1) * DM) + sl1;
                u64 v;
                for (;;) {
                    v = __hip_atomic_load(hp, __ATOMIC_RELAXED, __HIP_MEMORY_SCOPE_AGENT);
                    if (!has_sent_(v)) break;
                    PAUSE(S_RETRY);
                }
                ((u64*)&h1st[par][0])[sl1] = v;
            }
            __syncthreads();              // B1: both vectors staged

            const uint4* hb = m ? &h1st[par][0] : &h0st[par][0];
            float acc = 0.f;
#pragma unroll
            for (int j = 0; j < 16; j++)
                acc = dot8a_(wq[j], hb[c + 8 * j], acc);
            acc += __shfl_xor(acc, 1, 64);
            acc += __shfl_xor(acc, 2, 64);
            acc += __shfl_xor(acc, 4, 64);
            if (ldr) pre[rowid] = acc;    // pre[8s + 4m + g]
            __syncthreads();              // B2: pre[] complete

            if (pub) {                    // wave-0 lane tid = state tid
                float4 pa = *(const float4*)&pre[8 * tid];       // Wih1 part
                float4 pb = *(const float4*)&pre[8 * tid + 4];   // Whh1 part
                float pi = pa.x + pb.x + bsum[0];
                float pf = pa.y + pb.y + bsum[1];
                float pg = pa.z + pb.z + bsum[2];
                float po = pa.w + pb.w + bsum[3];
                float i_ = sigmoidf_(pi), f_ = sigmoidf_(pf);
                float g_ = tanhf_(pg),    o_ = sigmoidf_(po);
                c1  = f_ * c1 + i_ * g_;
                h1v = o_ * tanhf_(c1);
                u32 q = pk2_(h1v, h1v);
                // 16 consecutive lanes -> ONE coalesced 32B store
                __hip_atomic_store(h1h + (size_t)t * DM + 16 * u + tid,
                                   (u16)(q & 0xFFFFu),
                                   __ATOMIC_RELAXED, __HIP_MEMORY_SCOPE_AGENT);
            }
            // Hazards: h0st/h1st[par] written pre-B1(t), read (dot) between
            // B1(t) and B2(t); next same-parity write pre-B1(t+2) is after
            // B2(t+1) -> >=2 barriers separate. pre[] write(t+1) is post-
            // B1(t+1), which wave 0 only passes after its post-B2(t) reads.
        }
        if (pub) out[16 * u + tid] = lrelu_(h1v);   // h1[T-1]
    }
}

// ---------------------------------------------------------------------------
extern "C" void kernel_launch(void* const* d_in, const int* in_sizes, int n_in,
                              void* d_out, int out_size, void* d_ws, size_t ws_size,
                              hipStream_t stream) {
    const float* inp = (const float*)d_in[0];   // 4096 x 64
    const float* W1  = (const float*)d_in[1];   // 1024 x 64
    const float* b1  = (const float*)d_in[2];   // 1024
    const float* Wih = (const float*)d_in[3];   // 2 x 4096 x 1024
    const float* Whh = (const float*)d_in[4];   // 2 x 4096 x 1024
    const float* bih = (const float*)d_in[5];   // 2 x 4096
    const float* bhh = (const float*)d_in[6];   // 2 x 4096
    float* out = (float*)d_out;                 // 1024

    // workspace layout (unchanged):
    //   x: 4096*1024 f32 (16 MB; K1 out, K2 in) -> dead after K2, REUSED as
    //      h0h (8 MB f16) + h1h (8 MB f16) sentinel histories
    //   xg: 4096*4096 f32 (64 MB)
    float* x   = (float*)d_ws;
    float* xg  = x + (size_t)T_SEQ * DM;
    u16*   h0h = (u16*)d_ws;
    u16*   h1h = (u16*)d_ws + (size_t)T_SEQ * DM;
    (void)in_sizes; (void)n_in; (void)out_size; (void)ws_size;

    // Phase 1: input projection
    k_input<<<dim3(T_SEQ), dim3(256), 0, stream>>>(inp, W1, b1, x);

    // Phase 2: xg = x @ Wih0^T + (bih0+bhh0)
    k_gemm<<<dim3(32, 32), dim3(256), 0, stream>>>(x, Wih, bih, bhh, xg);

    // Phase 2b: x is dead -> sentinel-clear both histories (16 MB)
    k_clear<<<dim3(4096), dim3(256), 0, stream>>>((u32*)d_ws);

    // Phase 3: coarse-granularity decoupled scans (32 L0 + 64 L1 WGs, 1024 thr)
    k_scan<<<dim3(96), dim3(1024), 0, stream>>>(
        xg, Wih + LSTRIDE_W, Whh, Whh + LSTRIDE_W,
        bih + LSTRIDE_B, bhh + LSTRIDE_B, h0h, h1h, out);
}